// Round 1
// baseline (201.610 us; speedup 1.0000x reference)
//
#include <hip/hip_runtime.h>

// FeatureVolume: left/right [B=2, H=256, W=256, C=16] f32
// out [B, 2D=48, H, W, 2C=32] f32
// out[b,d,h,w, 0:16] = valid ? left [b,h,w,:]                  : 0
// out[b,d,h,w,16:32] = valid ? right[b,h,w-(d-24),:]           : 0
// valid = 0 <= w-(d-24) < W
//
// Memory-bound: 805 MB write, 16 MB read (cache-resident). One float4/lane.

#define MAXD 24
#define ND   48   // 2*MAXD
#define NB   2
#define HH   256
#define WW   256
// C=16 floats -> 4 float4 per (b,h,w); out row 2C=32 floats -> 8 float4

__global__ __launch_bounds__(256) void FeatureVolume_68762426409246_kernel(
    const float4* __restrict__ left,
    const float4* __restrict__ right,
    float4* __restrict__ out,
    unsigned int total_f4) {
    unsigned int stride = gridDim.x * blockDim.x;
    for (unsigned int f = blockIdx.x * blockDim.x + threadIdx.x; f < total_f4; f += stride) {
        // flat float4 index decode (all pow2 except b/d split):
        // f = (((b*ND + d)*HH + h)*WW + w)*8 + c4
        unsigned int c4 = f & 7u;            // which float4 of the 32-float row
        unsigned int w  = (f >> 3) & 255u;
        unsigned int h  = (f >> 11) & 255u;
        unsigned int bd = f >> 19;           // b*48 + d, in [0, 96)
        unsigned int b  = (bd >= ND) ? 1u : 0u;
        unsigned int d  = bd - b * ND;

        int src_w = (int)w - ((int)d - MAXD);            // w - disparity
        bool valid = ((unsigned)src_w < (unsigned)WW);

        float4 val = make_float4(0.f, 0.f, 0.f, 0.f);
        if (valid) {
            if (c4 < 4u) {
                // left half: left[b,h,w, c4]
                val = left[(((b * HH + h) * WW + w) << 2) + c4];
            } else {
                // right half: right[b,h,src_w, c4-4]
                val = right[(((b * HH + h) * WW + (unsigned)src_w) << 2) + (c4 - 4u)];
            }
        }
        out[f] = val;
    }
}

extern "C" void kernel_launch(void* const* d_in, const int* in_sizes, int n_in,
                              void* d_out, int out_size, void* d_ws, size_t ws_size,
                              hipStream_t stream) {
    const float4* left  = (const float4*)d_in[0];
    const float4* right = (const float4*)d_in[1];
    float4* out = (float4*)d_out;

    unsigned int total_f4 = (unsigned int)(out_size / 4);  // 50,331,648

    const int block = 256;
    const int grid  = 2048;  // 256 CU x 8 blocks, grid-stride the rest
    FeatureVolume_68762426409246_kernel<<<grid, block, 0, stream>>>(
        left, right, out, total_f4);
}

// Round 2
// 152.443 us; speedup vs baseline: 1.3225x; 1.3225x over previous
//
#include <hip/hip_runtime.h>

// FeatureVolume: left/right [B=2, H=256, W=256, C=16] f32
// out [B, 2D=48, H, W, 2C=32] f32
// out[b,d,h,w, 0:16] = valid ? left [b,h,w,:]        : 0
// out[b,d,h,w,16:32] = valid ? right[b,h,w-(d-24),:] : 0
// valid = 0 <= w-(d-24) < W
//
// Strategy: one block per (b,h). Stage left/right rows (16KB each) in LDS,
// then stream the 1.5 MB output slice (48 d x 256 w x 8 float4) with
// branchless LDS reads + coalesced global stores. Global reads: 32 MB total.

#define MAXD 24
#define ND   48
#define HH   256
#define WW   256
// C=16 floats = 4 float4 per pixel; out row = 2C = 8 float4

__global__ __launch_bounds__(1024) void FeatureVolume_68762426409246_kernel(
    const float4* __restrict__ left,
    const float4* __restrict__ right,
    float4* __restrict__ out) {
    // [half][w][c4] : 2 * 256 * 4 float4 = 32 KB
    __shared__ float4 lds[2 * WW * 4];

    const unsigned int bh  = blockIdx.x;      // b*HH + h
    const unsigned int b   = bh >> 8;
    const unsigned int tid = threadIdx.x;     // 0..1023

    // Stage input rows: each row is WW*4 = 1024 float4, one per thread.
    const unsigned int row_base = bh * (WW * 4);
    lds[tid]          = left [row_base + tid];
    lds[WW * 4 + tid] = right[row_base + tid];
    __syncthreads();

    // out float4 index = (((b*ND + d)*HH + h)*WW + w)*8 + c4
    //                  = out_base + d*(HH*WW*8) + (w*8 + c4)
    const unsigned int out_base = (b * (ND * HH) + (bh & 255u)) * (WW * 8);

    const unsigned int total = ND * WW * 8;   // 98304 float4 per (b,h)
    for (unsigned int idx = tid; idx < total; idx += 1024) {
        unsigned int c4 = idx & 7u;
        unsigned int w  = (idx >> 3) & 255u;
        unsigned int d  = idx >> 11;          // 0..47

        int src_w  = (int)w - ((int)d - MAXD);
        bool valid = ((unsigned)src_w < (unsigned)WW);

        // branchless source select: left half reads col=w, right half reads
        // clamped src_w; invalid lanes are zeroed by the mask afterwards.
        int col_r = min(max(src_w, 0), WW - 1);
        unsigned int col  = (c4 < 4u) ? w : (unsigned)col_r;
        unsigned int half = (c4 < 4u) ? 0u : (unsigned)(WW * 4);

        float4 v = lds[half + col * 4u + (c4 & 3u)];
        float  m = valid ? 1.0f : 0.0f;

        out[out_base + d * (HH * WW * 8) + (idx & 2047u)] =
            make_float4(v.x * m, v.y * m, v.z * m, v.w * m);
    }
}

extern "C" void kernel_launch(void* const* d_in, const int* in_sizes, int n_in,
                              void* d_out, int out_size, void* d_ws, size_t ws_size,
                              hipStream_t stream) {
    const float4* left  = (const float4*)d_in[0];
    const float4* right = (const float4*)d_in[1];
    float4* out = (float4*)d_out;

    // one block per (b,h): 2*256 = 512 blocks, 1024 threads each
    FeatureVolume_68762426409246_kernel<<<2 * HH, 1024, 0, stream>>>(
        left, right, out);
}